// Round 1
// baseline (328.449 us; speedup 1.0000x reference)
//
#include <hip/hip_runtime.h>

// CornerActivationB: ARITY=2, GROUPS=512, OUT_DIM=16, BATCH=8192, ACT_FACTOR=1
//
// Math note: the reference's 3-point hat-weight contraction against the
// lo/mid/hi expanded params collapses exactly to bilinear interpolation
// over the 4 original corners:
//   u1 = (clip(x,-1,1)+1)*0.5 ; u0 = 1-u1   (per input dim)
//   out[d] = sum_{b0,b1} u0[b0]*u1[b1] * params[g, 2*b0+b1, d]
// so we never materialize expand_params.

#define BATCH   8192
#define GROUPS  512
#define OUT_DIM 16

__global__ __launch_bounds__(256) void corner_act_kernel(
    const float* __restrict__ X,    // [BATCH, GROUPS*2]
    const float* __restrict__ P,    // [GROUPS, 4, OUT_DIM]
    float* __restrict__ out)        // [BATCH, GROUPS*OUT_DIM]
{
    // one thread = one float4 of output
    // idx = b*2048 + g*4 + q  ->  out float4 index == idx, X float2 index == idx>>2
    const int idx = blockIdx.x * 256 + threadIdx.x;
    const int q = idx & 3;
    const int g = (idx >> 2) & (GROUPS - 1);

    const float2 x = ((const float2*)X)[idx >> 2];
    const float a = (fminf(fmaxf(x.x, -1.0f), 1.0f) + 1.0f) * 0.5f; // dim0 hi-weight
    const float b = (fminf(fmaxf(x.y, -1.0f), 1.0f) + 1.0f) * 0.5f; // dim1 hi-weight

    const float w00 = (1.0f - a) * (1.0f - b);
    const float w01 = (1.0f - a) * b;
    const float w10 = a * (1.0f - b);
    const float w11 = a * b;

    // params quad for this (g, q): corner j lives at float4 offset j*4 + q
    const float4* p = (const float4*)(P + g * 64) + q;
    const float4 p0 = p[0];
    const float4 p1 = p[4];
    const float4 p2 = p[8];
    const float4 p3 = p[12];

    float4 o;
    o.x = w00 * p0.x + w01 * p1.x + w10 * p2.x + w11 * p3.x;
    o.y = w00 * p0.y + w01 * p1.y + w10 * p2.y + w11 * p3.y;
    o.z = w00 * p0.z + w01 * p1.z + w10 * p2.z + w11 * p3.z;
    o.w = w00 * p0.w + w01 * p1.w + w10 * p2.w + w11 * p3.w;

    ((float4*)out)[idx] = o;
}

extern "C" void kernel_launch(void* const* d_in, const int* in_sizes, int n_in,
                              void* d_out, int out_size, void* d_ws, size_t ws_size,
                              hipStream_t stream) {
    const float* X = (const float*)d_in[0];   // BATCH * GROUPS*2 fp32
    const float* P = (const float*)d_in[1];   // GROUPS * 4 * OUT_DIM fp32
    float* out = (float*)d_out;               // BATCH * GROUPS*OUT_DIM fp32

    const int total_f4 = BATCH * GROUPS * (OUT_DIM / 4);  // 16M float4s
    const int block = 256;
    const int grid = total_f4 / block;                    // 65536
    corner_act_kernel<<<grid, block, 0, stream>>>(X, P, out);
}

// Round 5
// 297.896 us; speedup vs baseline: 1.1026x; 1.1026x over previous
//
#include <hip/hip_runtime.h>

// CornerActivationB: ARITY=2, GROUPS=512, OUT_DIM=16, BATCH=8192, ACT_FACTOR=1
//
// Math: the 3-point hat-weight contraction against lo/mid/hi expanded params
// collapses exactly to bilinear interpolation over the 4 original corners:
//   a = (clip(x0,-1,1)+1)/2 ; b = (clip(x1,-1,1)+1)/2
//   out[d] = (1-a)(1-b) P[g,0,d] + (1-a)b P[g,1,d] + a(1-b) P[g,2,d] + ab P[g,3,d]
//
// Structure: P cached in REGISTERS (each thread owns its (g,q) column's 4
// corner vec4s = 16 VGPRs), block loops over 32 batch rows. Inner loop is
// one vec2 load + 16 FMA + one vec4 store — pure streaming.
// R5 fix: X row stride is 512 in float2 units (1024 floats/row), NOT 1024.
// R2-R4 read up to 2x past the end of X -> memory fault -> pytest abort.

#define BATCH   8192
#define GROUPS  512
#define OUT_DIM 16
#define GCHUNK  64      // groups per block (256 threads / 4 quads)
#define BITER   32      // batch rows per block

typedef float v4f __attribute__((ext_vector_type(4)));
typedef float v2f __attribute__((ext_vector_type(2)));

__global__ __launch_bounds__(256) void corner_act_kernel(
    const float* __restrict__ X,    // [BATCH, GROUPS*2]
    const float* __restrict__ P,    // [GROUPS, 4, OUT_DIM]
    float* __restrict__ out)        // [BATCH, GROUPS*OUT_DIM]
{
    const int t  = threadIdx.x;
    const int q  = t & 3;                       // which vec4 of OUT_DIM
    const int g  = blockIdx.x * GCHUNK + (t >> 2);

    // hoist this thread's 4 corner vectors into registers (once per block)
    const v4f* p = (const v4f*)P + g * 16 + q;
    const v4f p0 = p[0];     // corner (lo,lo)
    const v4f p1 = p[4];     // corner (lo,hi)
    const v4f p2 = p[8];     // corner (hi,lo)
    const v4f p3 = p[12];    // corner (hi,hi)

    // X row stride: 1024 floats = 512 v2f.  Out row stride: 8192 floats = 2048 v4f.
    const v2f* __restrict__ Xv = (const v2f*)X + g;            // + b*512 per row
    v4f* __restrict__ Ov = (v4f*)out + blockIdx.x * 256 + t;   // + b*2048 per row

    const int b0 = blockIdx.y * BITER;

    #pragma unroll 4
    for (int i = 0; i < BITER; ++i) {
        const int b = b0 + i;
        const v2f x = Xv[b * 512];

        const float a  = (fminf(fmaxf(x.x, -1.0f), 1.0f) + 1.0f) * 0.5f;
        const float bb = (fminf(fmaxf(x.y, -1.0f), 1.0f) + 1.0f) * 0.5f;
        const float w00 = (1.0f - a) * (1.0f - bb);
        const float w01 = (1.0f - a) * bb;
        const float w10 = a * (1.0f - bb);
        const float w11 = a * bb;

        Ov[b * 2048] = w00 * p0 + w01 * p1 + w10 * p2 + w11 * p3;
    }
}

extern "C" void kernel_launch(void* const* d_in, const int* in_sizes, int n_in,
                              void* d_out, int out_size, void* d_ws, size_t ws_size,
                              hipStream_t stream) {
    const float* X = (const float*)d_in[0];   // BATCH * GROUPS*2 fp32
    const float* P = (const float*)d_in[1];   // GROUPS * 4 * OUT_DIM fp32
    float* out = (float*)d_out;               // BATCH * GROUPS*OUT_DIM fp32

    dim3 grid(GROUPS / GCHUNK, BATCH / BITER);   // (8, 256) = 2048 blocks
    corner_act_kernel<<<grid, dim3(256), 0, stream>>>(X, P, out);
}

// Round 6
// 291.027 us; speedup vs baseline: 1.1286x; 1.0236x over previous
//
#include <hip/hip_runtime.h>

// CornerActivationB: ARITY=2, GROUPS=512, OUT_DIM=16, BATCH=8192, ACT_FACTOR=1
//
// Math: the 3-point hat-weight contraction against lo/mid/hi expanded params
// collapses exactly to bilinear interpolation over the 4 original corners:
//   a = (clip(x0,-1,1)+1)/2 ; b = (clip(x1,-1,1)+1)/2
//   out[d] = (1-a)(1-b) P[g,0,d] + (1-a)b P[g,1,d] + a(1-b) P[g,2,d] + ab P[g,3,d]
//
// Structure: P cached in REGISTERS (each thread owns its (g,q) column's 4
// corner vec4s = 16 VGPRs), block loops over 32 batch rows. Inner loop is
// one nontemporal vec2 load + 16 FMA + one nontemporal vec4 store.
// R6: nontemporal load/store (out is write-once, X is read-once — keep them
// out of L2 so the P table stays resident) + pointer-bump addressing.

#define BATCH   8192
#define GROUPS  512
#define OUT_DIM 16
#define GCHUNK  64      // groups per block (256 threads / 4 quads)
#define BITER   32      // batch rows per block

typedef float v4f __attribute__((ext_vector_type(4)));
typedef float v2f __attribute__((ext_vector_type(2)));

__global__ __launch_bounds__(256) void corner_act_kernel(
    const float* __restrict__ X,    // [BATCH, GROUPS*2]
    const float* __restrict__ P,    // [GROUPS, 4, OUT_DIM]
    float* __restrict__ out)        // [BATCH, GROUPS*OUT_DIM]
{
    const int t  = threadIdx.x;
    const int q  = t & 3;                       // which vec4 of OUT_DIM
    const int g  = blockIdx.x * GCHUNK + (t >> 2);

    // hoist this thread's 4 corner vectors into registers (once per block)
    const v4f* p = (const v4f*)P + g * 16 + q;
    const v4f p0 = p[0];     // corner (lo,lo)
    const v4f p1 = p[4];     // corner (lo,hi)
    const v4f p2 = p[8];     // corner (hi,lo)
    const v4f p3 = p[12];    // corner (hi,hi)

    // X row stride: 1024 floats = 512 v2f.  Out row stride: 8192 floats = 2048 v4f.
    const int b0 = blockIdx.y * BITER;
    const v2f* __restrict__ Xv = (const v2f*)X + g + (size_t)b0 * 512;
    v4f* __restrict__ Ov = (v4f*)out + blockIdx.x * 256 + t + (size_t)b0 * 2048;

    #pragma unroll 4
    for (int i = 0; i < BITER; ++i) {
        const v2f x = __builtin_nontemporal_load(Xv);

        const float a  = (fminf(fmaxf(x.x, -1.0f), 1.0f) + 1.0f) * 0.5f;
        const float bb = (fminf(fmaxf(x.y, -1.0f), 1.0f) + 1.0f) * 0.5f;
        const float w00 = (1.0f - a) * (1.0f - bb);
        const float w01 = (1.0f - a) * bb;
        const float w10 = a * (1.0f - bb);
        const float w11 = a * bb;

        const v4f o = w00 * p0 + w01 * p1 + w10 * p2 + w11 * p3;
        __builtin_nontemporal_store(o, Ov);

        Xv += 512;
        Ov += 2048;
    }
}

extern "C" void kernel_launch(void* const* d_in, const int* in_sizes, int n_in,
                              void* d_out, int out_size, void* d_ws, size_t ws_size,
                              hipStream_t stream) {
    const float* X = (const float*)d_in[0];   // BATCH * GROUPS*2 fp32
    const float* P = (const float*)d_in[1];   // GROUPS * 4 * OUT_DIM fp32
    float* out = (float*)d_out;               // BATCH * GROUPS*OUT_DIM fp32

    dim3 grid(GROUPS / GCHUNK, BATCH / BITER);   // (8, 256) = 2048 blocks
    corner_act_kernel<<<grid, dim3(256), 0, stream>>>(X, P, out);
}